// Round 19
// baseline (244.841 us; speedup 1.0000x reference)
//
#include <hip/hip_runtime.h>
#include <math.h>

#define F_IN  512
#define F_HID 256
#define F_OUT 64

typedef __attribute__((ext_vector_type(8))) short bf16x8;
typedef __attribute__((ext_vector_type(4))) short bf16x4;
typedef __attribute__((ext_vector_type(4))) float f32x4;

#define GLOBAL_AS __attribute__((address_space(1)))
#define LDS_AS    __attribute__((address_space(3)))

__device__ __forceinline__ void gload_lds16(const void* g, void* l) {
    __builtin_amdgcn_global_load_lds((const GLOBAL_AS uint32_t*)g,
                                     (LDS_AS uint32_t*)l, 16, 0, 0);
}

__device__ __forceinline__ ushort f2bf(float f) {
    union { float f; uint32_t u; } v; v.f = f;
    uint32_t r = (v.u + 0x7FFFu + ((v.u >> 16) & 1u)) >> 16;
    return (ushort)r;
}

__device__ __forceinline__ float bf2f(ushort u) {
    union { uint32_t u; float f; } v; v.u = ((uint32_t)u) << 16;
    return v.f;
}

__device__ __forceinline__ bf16x8 conv8(float4 a, float4 b) {
    bf16x8 c;
    c[0] = (short)f2bf(a.x); c[1] = (short)f2bf(a.y);
    c[2] = (short)f2bf(a.z); c[3] = (short)f2bf(a.w);
    c[4] = (short)f2bf(b.x); c[5] = (short)f2bf(b.y);
    c[6] = (short)f2bf(b.z); c[7] = (short)f2bf(b.w);
    return c;
}

// ---------------- prep: deg zero + coalesced LDS-tile transpose-casts ----------------
__global__ __launch_bounds__(256) void k_prep(
        const float* __restrict__ W1, ushort* __restrict__ w1t,
        const float* __restrict__ W2, ushort* __restrict__ w2t,
        int* __restrict__ deg, int N) {
    __shared__ ushort t[32][33];
    int bid = blockIdx.x;
    for (int i = bid * 256 + threadIdx.x; i < N; i += 144 * 256) deg[i] = 0;
    const float* W; ushort* Wt; int K, Nc, tk, tn;
    if (bid < 128) { W = W1; Wt = w1t; K = 512; Nc = 256; tk = bid >> 3; tn = bid & 7; }
    else { int b = bid - 128; W = W2; Wt = w2t; K = 256; Nc = 64; tk = b >> 1; tn = b & 1; }
    int r = threadIdx.x >> 5, c = threadIdx.x & 31;
    #pragma unroll
    for (int l = 0; l < 4; ++l)
        t[r + l * 8][c] = f2bf(W[(size_t)(tk * 32 + r + l * 8) * Nc + tn * 32 + c]);
    __syncthreads();
    #pragma unroll
    for (int l = 0; l < 4; ++l)
        Wt[(size_t)(tn * 32 + r + l * 8) * K + tk * 32 + c] = t[c][r + l * 8];
}

// ---------------- degree histogram (separate launch: max parallelism) ----------------
__global__ void k_deg(const int* __restrict__ dst, int* __restrict__ deg, int E) {
    int e = blockIdx.x * 256 + threadIdx.x;
    if (e < E) atomicAdd(&deg[dst[e]], 1);
}

// ---------------- scan level 1 (+ dinv fused) ----------------
__global__ void k_scan1(const int* __restrict__ deg, int* __restrict__ offs,
                        int* __restrict__ bsums, float* __restrict__ dinv, int N) {
    __shared__ int s[256];
    int tid = threadIdx.x;
    int i = blockIdx.x * 256 + tid;
    int v = (i < N) ? deg[i] : 0;
    if (i < N) dinv[i] = rsqrtf((float)(v + 1));   // +1 self loop
    s[tid] = v; __syncthreads();
    for (int d = 1; d < 256; d <<= 1) {
        int t = (tid >= d) ? s[tid - d] : 0;
        __syncthreads();
        s[tid] += t;
        __syncthreads();
    }
    if (i < N) offs[i] = s[tid] - v;
    if (tid == 255) bsums[blockIdx.x] = s[255];
}

__global__ void k_scan2(int* __restrict__ bsums, int n) {
    __shared__ int s[256];
    int tid = threadIdx.x;
    int v = (tid < n) ? bsums[tid] : 0;
    s[tid] = v; __syncthreads();
    for (int d = 1; d < 256; d <<= 1) {
        int t = (tid >= d) ? s[tid - d] : 0;
        __syncthreads();
        s[tid] += t;
        __syncthreads();
    }
    if (tid < n) bsums[tid] = s[tid] - v;
}

__global__ void k_scan3(int* __restrict__ offs, const int* __restrict__ bsums,
                        int* __restrict__ cursor, int2* __restrict__ jw, int N, int E) {
    int i = blockIdx.x * 256 + threadIdx.x;
    if (i < N) {
        int o = offs[i] + bsums[i >> 8];
        offs[i] = o;
        cursor[i] = o;
    }
    if (i == 0) offs[N] = E;
    if (i < 32) jw[E + i] = make_int2(0, 0);   // pad
}

__global__ void k_fill(const int* __restrict__ src, const int* __restrict__ dst,
                       int* __restrict__ cursor, int2* __restrict__ jw,
                       const float* __restrict__ dinv, int E) {
    int e = blockIdx.x * 256 + threadIdx.x;
    if (e < E) {
        int s = src[e];
        int pos = atomicAdd(&cursor[dst[e]], 1);
        jw[pos] = make_int2(s, __float_as_int(dinv[s]));
    }
}

// ---------------- GEMM1: h1 = bf16(x @ w1t^T) ----------------
// r15 structure (best measured, no atomics): BK=64, BM=64 x BN=128, 2x2 waves,
// double-buffered, 8-chunk XOR B swizzle, XCD pair-swizzle.
__global__ __launch_bounds__(256) void k_gemm1(
        const float* __restrict__ A, const ushort* __restrict__ Bt,
        ushort* __restrict__ C, int M, int nyblk) {
    constexpr int K = F_IN, Nc = F_HID, BM = 64, NT = K / 64;
    constexpr int ASTR = 72;
    __shared__ ushort As[2][BM * ASTR];
    __shared__ ushort Bs[2][128 * 64];
    const int tid  = threadIdx.x;
    const int wave = tid >> 6, lane = tid & 63;
    const int wr = wave & 1, wc = wave >> 1;
    const int l15 = lane & 15, hi = lane >> 4;

    int L = blockIdx.x;
    int nfull = (2 * nyblk) & ~15;
    int bx, by;
    if (L < nfull) { bx = (L >> 3) & 1; by = (L >> 4) * 8 + (L & 7); }
    else { int t = L - nfull; bx = t & 1; by = nfull / 2 + (t >> 1); }
    const int brow = by * BM, bcol = bx * 128;

    f32x4 acc[2][4];
    #pragma unroll
    for (int m = 0; m < 2; ++m)
        #pragma unroll
        for (int n = 0; n < 4; ++n) acc[m][n] = (f32x4){0.f, 0.f, 0.f, 0.f};

    const int arow = tid >> 2;
    const int akc  = (tid & 3) * 16;
    int agrow = brow + arow; if (agrow >= M) agrow = M - 1;
    const float4* ap = (const float4*)&A[(size_t)agrow * K + akc];
    const int bc = (lane & 7) ^ ((lane >> 3) & 7);
    const ushort* bp[4];
    int bdst[4];
    #pragma unroll
    for (int l = 0; l < 4; ++l) {
        int g = l * 4 + wave;
        int R = g * 8 + (lane >> 3);
        bp[l]   = &Bt[(size_t)(bcol + R) * K + bc * 8];
        bdst[l] = g * 512;
    }

    {
        float4 v0 = ap[0], v1 = ap[1], v2 = ap[2], v3 = ap[3];
        *(bf16x8*)&As[0][arow * ASTR + akc]     = conv8(v0, v1);
        *(bf16x8*)&As[0][arow * ASTR + akc + 8] = conv8(v2, v3);
        #pragma unroll
        for (int l = 0; l < 4; ++l) gload_lds16(bp[l], &Bs[0][bdst[l]]);
    }
    __syncthreads();

    #pragma unroll
    for (int t = 0; t < NT; ++t) {
        const int b = t & 1;
        if (t + 1 < NT) {
            #pragma unroll
            for (int l = 0; l < 4; ++l)
                gload_lds16(bp[l] + (t + 1) * 64, &Bs[b ^ 1][bdst[l]]);
            float4 v0 = ap[(t + 1) * 16], v1 = ap[(t + 1) * 16 + 1],
                   v2 = ap[(t + 1) * 16 + 2], v3 = ap[(t + 1) * 16 + 3];
            *(bf16x8*)&As[b ^ 1][arow * ASTR + akc]     = conv8(v0, v1);
            *(bf16x8*)&As[b ^ 1][arow * ASTR + akc + 8] = conv8(v2, v3);
        }
        #pragma unroll
        for (int ks = 0; ks < 2; ++ks) {
            const int kqA = ks * 32 + hi * 8;
            bf16x8 af[2], bfr[4];
            #pragma unroll
            for (int m = 0; m < 2; ++m)
                af[m] = *(const bf16x8*)&As[b][(wr * 32 + l15 + m * 16) * ASTR + kqA];
            #pragma unroll
            for (int n = 0; n < 4; ++n) {
                const int row = wc * 64 + l15 + n * 16;
                const int p = (ks * 4 + hi) ^ (l15 & 7);
                bfr[n] = *(const bf16x8*)&Bs[b][row * 64 + p * 8];
            }
            #pragma unroll
            for (int m = 0; m < 2; ++m)
                #pragma unroll
                for (int n = 0; n < 4; ++n)
                    acc[m][n] = __builtin_amdgcn_mfma_f32_16x16x32_bf16(af[m], bfr[n], acc[m][n], 0, 0, 0);
        }
        if (t + 1 < NT) __syncthreads();
    }

    const int crow0 = brow + wr * 32 + hi * 4;
    const int ccol0 = bcol + wc * 64 + l15;
    #pragma unroll
    for (int m = 0; m < 2; ++m)
        #pragma unroll
        for (int n = 0; n < 4; ++n)
            #pragma unroll
            for (int j = 0; j < 4; ++j) {
                int row = crow0 + m * 16 + j;
                if (row < M) C[(size_t)row * Nc + ccol0 + n * 16] = f2bf(acc[m][n][j]);
            }
}

// ---------------- bf16 MFMA GEMM2 ----------------
template<int WR, int WC, int MR, int NR>
__global__ __launch_bounds__(256) void k_gemm_bf16(
        const ushort* __restrict__ A, const ushort* __restrict__ Bt,
        ushort* __restrict__ C, int M, int K, int Nc) {
    constexpr int BM = WR * MR * 16;
    constexpr int BN = WC * NR * 16;
    __shared__ ushort As[BM * 32];
    __shared__ ushort Bs[BN * 32];
    const int tid  = threadIdx.x;
    const int wave = tid >> 6, lane = tid & 63;
    const int wr = wave % WR, wc = wave / WR;
    const int brow = blockIdx.y * BM, bcol = blockIdx.x * BN;

    f32x4 acc[MR][NR];
    #pragma unroll
    for (int m = 0; m < MR; ++m)
        #pragma unroll
        for (int n = 0; n < NR; ++n) acc[m][n] = (f32x4){0.f, 0.f, 0.f, 0.f};

    const int srow = tid >> 2;
    const int scol = (tid & 3) * 8;
    const int kq  = (lane >> 4) * 8;
    const int rA0 = wr * MR * 16 + (lane & 15);
    const int rB0 = wc * NR * 16 + (lane & 15);

    for (int k0 = 0; k0 < K; k0 += 32) {
        #pragma unroll
        for (int l = 0; l < BM / 64; ++l) {
            int row = brow + l * 64 + srow;
            if (row >= M) row = M - 1;
            gload_lds16(&A[(size_t)row * K + k0 + scol], &As[l * 2048 + wave * 512]);
        }
        #pragma unroll
        for (int l = 0; l < BN / 64; ++l) {
            int row = bcol + l * 64 + srow;
            gload_lds16(&Bt[(size_t)row * K + k0 + scol], &Bs[l * 2048 + wave * 512]);
        }
        __syncthreads();
        bf16x8 af[MR], bfr[NR];
        #pragma unroll
        for (int m = 0; m < MR; ++m)
            af[m] = *(const bf16x8*)&As[(rA0 + m * 16) * 32 + kq];
        #pragma unroll
        for (int n = 0; n < NR; ++n)
            bfr[n] = *(const bf16x8*)&Bs[(rB0 + n * 16) * 32 + kq];
        #pragma unroll
        for (int m = 0; m < MR; ++m)
            #pragma unroll
            for (int n = 0; n < NR; ++n)
                acc[m][n] = __builtin_amdgcn_mfma_f32_16x16x32_bf16(af[m], bfr[n], acc[m][n], 0, 0, 0);
        __syncthreads();
    }

    const int crow0 = brow + wr * MR * 16 + (lane >> 4) * 4;
    const int ccol0 = bcol + wc * NR * 16 + (lane & 15);
    #pragma unroll
    for (int m = 0; m < MR; ++m)
        #pragma unroll
        for (int n = 0; n < NR; ++n)
            #pragma unroll
            for (int j = 0; j < 4; ++j) {
                int row = crow0 + m * 16 + j;
                if (row < M) C[(size_t)row * Nc + ccol0 + n * 16] = f2bf(acc[m][n][j]);
            }
}

// ---------------- layer-1 aggregation: paired-row gathers, 16 edges/iter ----------------
__global__ __launch_bounds__(256) void k_agg1(
        const ushort* __restrict__ h, const int2* __restrict__ jw,
        const int* __restrict__ offs, const float* __restrict__ dinv,
        const float* __restrict__ bias, ushort* __restrict__ outm, int N) {
    int wave = threadIdx.x >> 6, lane = threadIdx.x & 63;
    int i = blockIdx.x * 4 + wave;
    if (i >= N) return;
    int g = lane & 31;
    int p = lane >> 5;
    float di = dinv[i];
    float acc[8];
    {
        bf16x8 hv = *(const bf16x8*)&h[(size_t)i * F_HID + g * 8];
        float w = (p == 0) ? di * di : 0.f;
        #pragma unroll
        for (int k = 0; k < 8; ++k) acc[k] = bf2f((ushort)hv[k]) * w;
    }
    int s = offs[i], e = offs[i + 1];
    for (int u = s; u < e; u += 16) {
        int2 a[8];
        #pragma unroll
        for (int q = 0; q < 8; ++q) a[q] = jw[u + 2 * q + p];
        bf16x8 hv[8];
        #pragma unroll
        for (int q = 0; q < 8; ++q)
            hv[q] = *(const bf16x8*)&h[(size_t)a[q].x * F_HID + g * 8];
        #pragma unroll
        for (int q = 0; q < 8; ++q) {
            float ww = (u + 2 * q + p < e) ? __int_as_float(a[q].y) * di : 0.f;
            #pragma unroll
            for (int k = 0; k < 8; ++k) acc[k] += bf2f((ushort)hv[q][k]) * ww;
        }
    }
    #pragma unroll
    for (int k = 0; k < 8; ++k) acc[k] += __shfl_xor(acc[k], 32, 64);
    if (p == 0) {
        float4 b0 = *(const float4*)&bias[g * 8];
        float4 b1 = *(const float4*)&bias[g * 8 + 4];
        bf16x8 o;
        o[0] = (short)f2bf(fmaxf(acc[0] + b0.x, 0.f));
        o[1] = (short)f2bf(fmaxf(acc[1] + b0.y, 0.f));
        o[2] = (short)f2bf(fmaxf(acc[2] + b0.z, 0.f));
        o[3] = (short)f2bf(fmaxf(acc[3] + b0.w, 0.f));
        o[4] = (short)f2bf(fmaxf(acc[4] + b1.x, 0.f));
        o[5] = (short)f2bf(fmaxf(acc[5] + b1.y, 0.f));
        o[6] = (short)f2bf(fmaxf(acc[6] + b1.z, 0.f));
        o[7] = (short)f2bf(fmaxf(acc[7] + b1.w, 0.f));
        *(bf16x8*)&outm[(size_t)i * F_HID + g * 8] = o;
    }
}

// ---------------- layer-2 aggregation + log_softmax: 4-parity paired gathers ----------------
__global__ __launch_bounds__(256) void k_agg2(
        const ushort* __restrict__ h, const int2* __restrict__ jw,
        const int* __restrict__ offs, const float* __restrict__ dinv,
        const float* __restrict__ bias, float* __restrict__ outm, int N) {
    int wave = threadIdx.x >> 6, lane = threadIdx.x & 63;
    int i = blockIdx.x * 4 + wave;
    if (i >= N) return;
    int g4 = lane & 15;
    int p  = lane >> 4;
    float di = dinv[i];
    float acc[4];
    {
        bf16x4 hv = *(const bf16x4*)&h[(size_t)i * F_OUT + g4 * 4];
        float w = (p == 0) ? di * di : 0.f;
        #pragma unroll
        for (int k = 0; k < 4; ++k) acc[k] = bf2f((ushort)hv[k]) * w;
    }
    int s = offs[i], e = offs[i + 1];
    for (int u = s; u < e; u += 32) {
        int2 a[8];
        #pragma unroll
        for (int q = 0; q < 8; ++q) a[q] = jw[u + 4 * q + p];
        bf16x4 hv[8];
        #pragma unroll
        for (int q = 0; q < 8; ++q)
            hv[q] = *(const bf16x4*)&h[(size_t)a[q].x * F_OUT + g4 * 4];
        #pragma unroll
        for (int q = 0; q < 8; ++q) {
            float ww = (u + 4 * q + p < e) ? __int_as_float(a[q].y) * di : 0.f;
            #pragma unroll
            for (int k = 0; k < 4; ++k) acc[k] += bf2f((ushort)hv[q][k]) * ww;
        }
    }
    #pragma unroll
    for (int k = 0; k < 4; ++k) {
        acc[k] += __shfl_xor(acc[k], 16, 64);
        acc[k] += __shfl_xor(acc[k], 32, 64);
    }
    float4 bv = *(const float4*)&bias[g4 * 4];
    acc[0] += bv.x; acc[1] += bv.y; acc[2] += bv.z; acc[3] += bv.w;
    float m = fmaxf(fmaxf(acc[0], acc[1]), fmaxf(acc[2], acc[3]));
    #pragma unroll
    for (int o = 8; o >= 1; o >>= 1) m = fmaxf(m, __shfl_xor(m, o, 64));
    float ssum = expf(acc[0] - m) + expf(acc[1] - m) + expf(acc[2] - m) + expf(acc[3] - m);
    #pragma unroll
    for (int o = 8; o >= 1; o >>= 1) ssum += __shfl_xor(ssum, o, 64);
    float lse = m + logf(ssum);
    if (p == 0) {
        float4 o4;
        o4.x = acc[0] - lse; o4.y = acc[1] - lse;
        o4.z = acc[2] - lse; o4.w = acc[3] - lse;
        *(float4*)&outm[(size_t)i * F_OUT + g4 * 4] = o4;
    }
}

extern "C" void kernel_launch(void* const* d_in, const int* in_sizes, int n_in,
                              void* d_out, int out_size, void* d_ws, size_t ws_size,
                              hipStream_t stream) {
    const float* x  = (const float*)d_in[0];
    const int*   ei = (const int*)d_in[1];
    const float* W1 = (const float*)d_in[2];
    const float* b1 = (const float*)d_in[3];
    const float* W2 = (const float*)d_in[4];
    const float* b2 = (const float*)d_in[5];
    float* out = (float*)d_out;

    int N = in_sizes[0] / F_IN;   // 50000
    int E = in_sizes[1] / 2;      // 800000
    const int* src = ei;
    const int* dst = ei + E;

    // workspace layout (16B aligned by construction)
    ushort* w1t = (ushort*)d_ws;                        // 256*512
    ushort* w2t = w1t + F_HID * F_IN;                   // 64*256
    ushort* h1  = w2t + F_OUT * F_HID;                  // N*256 bf16
    ushort* a1  = h1 + (size_t)N * F_HID;               // N*256 bf16
    int*    deg = (int*)(a1 + (size_t)N * F_HID);       // N
    float*  dinv = (float*)(deg + N);                   // N
    int*    offs = (int*)(dinv + N);                    // N+1
    int*    cursor = offs + N + 1;                      // N
    int*    bsums  = cursor + N;                        // 256
    int2*   jw = (int2*)(((uintptr_t)(bsums + 256) + 7) & ~(uintptr_t)7);  // E+32
    ushort* h2 = h1;     // alias: h1 dead after agg1

    int nch = (N + 255) / 256;
    int nyblk = (N + 63) / 64;

    // 1) zero deg + coalesced transpose-casts of W1/W2
    k_prep<<<144, 256, 0, stream>>>(W1, w1t, W2, w2t, deg, N);

    // 2) degree histogram (separate, 3125 blocks: max parallelism for atomics)
    k_deg<<<(E + 255) / 256, 256, 0, stream>>>(dst, deg, E);

    // 3) fused cast+GEMM layer 1 (no atomics)
    k_gemm1<<<2 * nyblk, 256, 0, stream>>>(x, w1t, h1, N, nyblk);

    // 4-7) CSR build: scan1+dinv / scan2 / scan3+pad / fill
    k_scan1<<<nch, 256, 0, stream>>>(deg, offs, bsums, dinv, N);
    k_scan2<<<1, 256, 0, stream>>>(bsums, nch);
    k_scan3<<<nch, 256, 0, stream>>>(offs, bsums, cursor, jw, N, E);
    k_fill<<<(E + 255) / 256, 256, 0, stream>>>(src, dst, cursor, jw, dinv, E);

    // 8) layer-1 aggregate
    k_agg1<<<(N + 3) / 4, 256, 0, stream>>>(h1, jw, offs, dinv, b1, a1, N);

    // 9) layer-2 GEMM
    k_gemm_bf16<4, 1, 1, 4><<<dim3(1, (N + 63) / 64), 256, 0, stream>>>(
        a1, w2t, h2, N, F_HID, F_OUT);

    // 10) layer-2 aggregate + log_softmax
    k_agg2<<<(N + 3) / 4, 256, 0, stream>>>(h2, jw, offs, dinv, b2, out, N);
}

// Round 20
// 222.744 us; speedup vs baseline: 1.0992x; 1.0992x over previous
//
#include <hip/hip_runtime.h>
#include <math.h>

#define F_IN  512
#define F_HID 256
#define F_OUT 64

typedef __attribute__((ext_vector_type(8))) short bf16x8;
typedef __attribute__((ext_vector_type(4))) short bf16x4;
typedef __attribute__((ext_vector_type(4))) float f32x4;

#define GLOBAL_AS __attribute__((address_space(1)))
#define LDS_AS    __attribute__((address_space(3)))

__device__ __forceinline__ void gload_lds16(const void* g, void* l) {
    __builtin_amdgcn_global_load_lds((const GLOBAL_AS uint32_t*)g,
                                     (LDS_AS uint32_t*)l, 16, 0, 0);
}

__device__ __forceinline__ ushort f2bf(float f) {
    union { float f; uint32_t u; } v; v.f = f;
    uint32_t r = (v.u + 0x7FFFu + ((v.u >> 16) & 1u)) >> 16;
    return (ushort)r;
}

__device__ __forceinline__ float bf2f(ushort u) {
    union { uint32_t u; float f; } v; v.u = ((uint32_t)u) << 16;
    return v.f;
}

__device__ __forceinline__ bf16x8 conv8(float4 a, float4 b) {
    bf16x8 c;
    c[0] = (short)f2bf(a.x); c[1] = (short)f2bf(a.y);
    c[2] = (short)f2bf(a.z); c[3] = (short)f2bf(a.w);
    c[4] = (short)f2bf(b.x); c[5] = (short)f2bf(b.y);
    c[6] = (short)f2bf(b.z); c[7] = (short)f2bf(b.w);
    return c;
}

// ---------------- prep: deg zero + coalesced LDS-tile transpose-casts ----------------
__global__ __launch_bounds__(256) void k_prep(
        const float* __restrict__ W1, ushort* __restrict__ w1t,
        const float* __restrict__ W2, ushort* __restrict__ w2t,
        int* __restrict__ deg, int N) {
    __shared__ ushort t[32][33];
    int bid = blockIdx.x;
    for (int i = bid * 256 + threadIdx.x; i < N; i += 144 * 256) deg[i] = 0;
    const float* W; ushort* Wt; int K, Nc, tk, tn;
    if (bid < 128) { W = W1; Wt = w1t; K = 512; Nc = 256; tk = bid >> 3; tn = bid & 7; }
    else { int b = bid - 128; W = W2; Wt = w2t; K = 256; Nc = 64; tk = b >> 1; tn = b & 1; }
    int r = threadIdx.x >> 5, c = threadIdx.x & 31;
    #pragma unroll
    for (int l = 0; l < 4; ++l)
        t[r + l * 8][c] = f2bf(W[(size_t)(tk * 32 + r + l * 8) * Nc + tn * 32 + c]);
    __syncthreads();
    #pragma unroll
    for (int l = 0; l < 4; ++l)
        Wt[(size_t)(tn * 32 + r + l * 8) * K + tk * 32 + c] = t[c][r + l * 8];
}

// ---------------- scan level 1 (+ dinv fused) ----------------
__global__ void k_scan1(const int* __restrict__ deg, int* __restrict__ offs,
                        int* __restrict__ bsums, float* __restrict__ dinv, int N) {
    __shared__ int s[256];
    int tid = threadIdx.x;
    int i = blockIdx.x * 256 + tid;
    int v = (i < N) ? deg[i] : 0;
    if (i < N) dinv[i] = rsqrtf((float)(v + 1));   // +1 self loop
    s[tid] = v; __syncthreads();
    for (int d = 1; d < 256; d <<= 1) {
        int t = (tid >= d) ? s[tid - d] : 0;
        __syncthreads();
        s[tid] += t;
        __syncthreads();
    }
    if (i < N) offs[i] = s[tid] - v;
    if (tid == 255) bsums[blockIdx.x] = s[255];
}

__global__ void k_scan2(int* __restrict__ bsums, int n) {
    __shared__ int s[256];
    int tid = threadIdx.x;
    int v = (tid < n) ? bsums[tid] : 0;
    s[tid] = v; __syncthreads();
    for (int d = 1; d < 256; d <<= 1) {
        int t = (tid >= d) ? s[tid - d] : 0;
        __syncthreads();
        s[tid] += t;
        __syncthreads();
    }
    if (tid < n) bsums[tid] = s[tid] - v;
}

__global__ void k_scan3(int* __restrict__ offs, const int* __restrict__ bsums,
                        int* __restrict__ cursor, int2* __restrict__ jw, int N, int E) {
    int i = blockIdx.x * 256 + threadIdx.x;
    if (i < N) {
        int o = offs[i] + bsums[i >> 8];
        offs[i] = o;
        cursor[i] = o;
    }
    if (i == 0) offs[N] = E;
    if (i < 32) jw[E + i] = make_int2(0, 0);   // pad
}

__global__ void k_fill(const int* __restrict__ src, const int* __restrict__ dst,
                       int* __restrict__ cursor, int2* __restrict__ jw,
                       const float* __restrict__ dinv, int E) {
    int e = blockIdx.x * 256 + threadIdx.x;
    if (e < E) {
        int s = src[e];
        int pos = atomicAdd(&cursor[dst[e]], 1);
        jw[pos] = make_int2(s, __float_as_int(dinv[s]));
    }
}

// ---------------- GEMM1 (+ interleaved degree histogram): h1 = bf16(x @ w1t^T) ----------------
// r15 structure: BK=64, BM=64 x BN=128, 2x2 waves, double-buffered, 8-chunk
// XOR B swizzle, XCD pair-swizzle. Deg atomics INTERLEAVED mid-loop (iters 1,4):
// their ack shares the barrier drain already waiting on staging loads, instead
// of serializing at the kernel tail (r18) or prologue (r17).
__global__ __launch_bounds__(256) void k_gemm1(
        const float* __restrict__ A, const ushort* __restrict__ Bt,
        ushort* __restrict__ C, int M, int nyblk,
        const int* __restrict__ dst, int* __restrict__ deg, int E) {
    constexpr int K = F_IN, Nc = F_HID, BM = 64, NT = K / 64;
    constexpr int ASTR = 72;
    __shared__ ushort As[2][BM * ASTR];
    __shared__ ushort Bs[2][128 * 64];
    const int tid  = threadIdx.x;
    const int wave = tid >> 6, lane = tid & 63;
    const int wr = wave & 1, wc = wave >> 1;
    const int l15 = lane & 15, hi = lane >> 4;

    int L = blockIdx.x;
    int nfull = (2 * nyblk) & ~15;
    int bx, by;
    if (L < nfull) { bx = (L >> 3) & 1; by = (L >> 4) * 8 + (L & 7); }
    else { int t = L - nfull; bx = t & 1; by = nfull / 2 + (t >> 1); }
    const int brow = by * BM, bcol = bx * 128;

    f32x4 acc[2][4];
    #pragma unroll
    for (int m = 0; m < 2; ++m)
        #pragma unroll
        for (int n = 0; n < 4; ++n) acc[m][n] = (f32x4){0.f, 0.f, 0.f, 0.f};

    const int arow = tid >> 2;
    const int akc  = (tid & 3) * 16;
    int agrow = brow + arow; if (agrow >= M) agrow = M - 1;
    const float4* ap = (const float4*)&A[(size_t)agrow * K + akc];
    const int bc = (lane & 7) ^ ((lane >> 3) & 7);
    const ushort* bp[4];
    int bdst[4];
    #pragma unroll
    for (int l = 0; l < 4; ++l) {
        int g = l * 4 + wave;
        int R = g * 8 + (lane >> 3);
        bp[l]   = &Bt[(size_t)(bcol + R) * K + bc * 8];
        bdst[l] = g * 512;
    }

    {
        float4 v0 = ap[0], v1 = ap[1], v2 = ap[2], v3 = ap[3];
        *(bf16x8*)&As[0][arow * ASTR + akc]     = conv8(v0, v1);
        *(bf16x8*)&As[0][arow * ASTR + akc + 8] = conv8(v2, v3);
        #pragma unroll
        for (int l = 0; l < 4; ++l) gload_lds16(bp[l], &Bs[0][bdst[l]]);
    }
    __syncthreads();

    #pragma unroll
    for (int t = 0; t < NT; ++t) {
        const int b = t & 1;
        if (t + 1 < NT) {
            #pragma unroll
            for (int l = 0; l < 4; ++l)
                gload_lds16(bp[l] + (t + 1) * 64, &Bs[b ^ 1][bdst[l]]);
            float4 v0 = ap[(t + 1) * 16], v1 = ap[(t + 1) * 16 + 1],
                   v2 = ap[(t + 1) * 16 + 2], v3 = ap[(t + 1) * 16 + 3];
            *(bf16x8*)&As[b ^ 1][arow * ASTR + akc]     = conv8(v0, v1);
            *(bf16x8*)&As[b ^ 1][arow * ASTR + akc + 8] = conv8(v2, v3);
        }
        // interleaved deg atomics: share the barrier drain with staging loads
        if (t == 1) {
            int e0 = blockIdx.x * 512 + tid;
            if (e0 < E) atomicAdd(&deg[dst[e0]], 1);
        }
        if (t == 4) {
            int e1 = blockIdx.x * 512 + 256 + tid;
            if (e1 < E) atomicAdd(&deg[dst[e1]], 1);
        }
        #pragma unroll
        for (int ks = 0; ks < 2; ++ks) {
            const int kqA = ks * 32 + hi * 8;
            bf16x8 af[2], bfr[4];
            #pragma unroll
            for (int m = 0; m < 2; ++m)
                af[m] = *(const bf16x8*)&As[b][(wr * 32 + l15 + m * 16) * ASTR + kqA];
            #pragma unroll
            for (int n = 0; n < 4; ++n) {
                const int row = wc * 64 + l15 + n * 16;
                const int p = (ks * 4 + hi) ^ (l15 & 7);
                bfr[n] = *(const bf16x8*)&Bs[b][row * 64 + p * 8];
            }
            #pragma unroll
            for (int m = 0; m < 2; ++m)
                #pragma unroll
                for (int n = 0; n < 4; ++n)
                    acc[m][n] = __builtin_amdgcn_mfma_f32_16x16x32_bf16(af[m], bfr[n], acc[m][n], 0, 0, 0);
        }
        if (t + 1 < NT) __syncthreads();
    }

    const int crow0 = brow + wr * 32 + hi * 4;
    const int ccol0 = bcol + wc * 64 + l15;
    #pragma unroll
    for (int m = 0; m < 2; ++m)
        #pragma unroll
        for (int n = 0; n < 4; ++n)
            #pragma unroll
            for (int j = 0; j < 4; ++j) {
                int row = crow0 + m * 16 + j;
                if (row < M) C[(size_t)row * Nc + ccol0 + n * 16] = f2bf(acc[m][n][j]);
            }
}

// ---------------- bf16 MFMA GEMM2 ----------------
template<int WR, int WC, int MR, int NR>
__global__ __launch_bounds__(256) void k_gemm_bf16(
        const ushort* __restrict__ A, const ushort* __restrict__ Bt,
        ushort* __restrict__ C, int M, int K, int Nc) {
    constexpr int BM = WR * MR * 16;
    constexpr int BN = WC * NR * 16;
    __shared__ ushort As[BM * 32];
    __shared__ ushort Bs[BN * 32];
    const int tid  = threadIdx.x;
    const int wave = tid >> 6, lane = tid & 63;
    const int wr = wave % WR, wc = wave / WR;
    const int brow = blockIdx.y * BM, bcol = blockIdx.x * BN;

    f32x4 acc[MR][NR];
    #pragma unroll
    for (int m = 0; m < MR; ++m)
        #pragma unroll
        for (int n = 0; n < NR; ++n) acc[m][n] = (f32x4){0.f, 0.f, 0.f, 0.f};

    const int srow = tid >> 2;
    const int scol = (tid & 3) * 8;
    const int kq  = (lane >> 4) * 8;
    const int rA0 = wr * MR * 16 + (lane & 15);
    const int rB0 = wc * NR * 16 + (lane & 15);

    for (int k0 = 0; k0 < K; k0 += 32) {
        #pragma unroll
        for (int l = 0; l < BM / 64; ++l) {
            int row = brow + l * 64 + srow;
            if (row >= M) row = M - 1;
            gload_lds16(&A[(size_t)row * K + k0 + scol], &As[l * 2048 + wave * 512]);
        }
        #pragma unroll
        for (int l = 0; l < BN / 64; ++l) {
            int row = bcol + l * 64 + srow;
            gload_lds16(&Bt[(size_t)row * K + k0 + scol], &Bs[l * 2048 + wave * 512]);
        }
        __syncthreads();
        bf16x8 af[MR], bfr[NR];
        #pragma unroll
        for (int m = 0; m < MR; ++m)
            af[m] = *(const bf16x8*)&As[(rA0 + m * 16) * 32 + kq];
        #pragma unroll
        for (int n = 0; n < NR; ++n)
            bfr[n] = *(const bf16x8*)&Bs[(rB0 + n * 16) * 32 + kq];
        #pragma unroll
        for (int m = 0; m < MR; ++m)
            #pragma unroll
            for (int n = 0; n < NR; ++n)
                acc[m][n] = __builtin_amdgcn_mfma_f32_16x16x32_bf16(af[m], bfr[n], acc[m][n], 0, 0, 0);
        __syncthreads();
    }

    const int crow0 = brow + wr * MR * 16 + (lane >> 4) * 4;
    const int ccol0 = bcol + wc * NR * 16 + (lane & 15);
    #pragma unroll
    for (int m = 0; m < MR; ++m)
        #pragma unroll
        for (int n = 0; n < NR; ++n)
            #pragma unroll
            for (int j = 0; j < 4; ++j) {
                int row = crow0 + m * 16 + j;
                if (row < M) C[(size_t)row * Nc + ccol0 + n * 16] = f2bf(acc[m][n][j]);
            }
}

// ---------------- layer-1 aggregation: paired-row gathers, 16 edges/iter ----------------
__global__ __launch_bounds__(256) void k_agg1(
        const ushort* __restrict__ h, const int2* __restrict__ jw,
        const int* __restrict__ offs, const float* __restrict__ dinv,
        const float* __restrict__ bias, ushort* __restrict__ outm, int N) {
    int wave = threadIdx.x >> 6, lane = threadIdx.x & 63;
    int i = blockIdx.x * 4 + wave;
    if (i >= N) return;
    int g = lane & 31;
    int p = lane >> 5;
    float di = dinv[i];
    float acc[8];
    {
        bf16x8 hv = *(const bf16x8*)&h[(size_t)i * F_HID + g * 8];
        float w = (p == 0) ? di * di : 0.f;
        #pragma unroll
        for (int k = 0; k < 8; ++k) acc[k] = bf2f((ushort)hv[k]) * w;
    }
    int s = offs[i], e = offs[i + 1];
    for (int u = s; u < e; u += 16) {
        int2 a[8];
        #pragma unroll
        for (int q = 0; q < 8; ++q) a[q] = jw[u + 2 * q + p];
        bf16x8 hv[8];
        #pragma unroll
        for (int q = 0; q < 8; ++q)
            hv[q] = *(const bf16x8*)&h[(size_t)a[q].x * F_HID + g * 8];
        #pragma unroll
        for (int q = 0; q < 8; ++q) {
            float ww = (u + 2 * q + p < e) ? __int_as_float(a[q].y) * di : 0.f;
            #pragma unroll
            for (int k = 0; k < 8; ++k) acc[k] += bf2f((ushort)hv[q][k]) * ww;
        }
    }
    #pragma unroll
    for (int k = 0; k < 8; ++k) acc[k] += __shfl_xor(acc[k], 32, 64);
    if (p == 0) {
        float4 b0 = *(const float4*)&bias[g * 8];
        float4 b1 = *(const float4*)&bias[g * 8 + 4];
        bf16x8 o;
        o[0] = (short)f2bf(fmaxf(acc[0] + b0.x, 0.f));
        o[1] = (short)f2bf(fmaxf(acc[1] + b0.y, 0.f));
        o[2] = (short)f2bf(fmaxf(acc[2] + b0.z, 0.f));
        o[3] = (short)f2bf(fmaxf(acc[3] + b0.w, 0.f));
        o[4] = (short)f2bf(fmaxf(acc[4] + b1.x, 0.f));
        o[5] = (short)f2bf(fmaxf(acc[5] + b1.y, 0.f));
        o[6] = (short)f2bf(fmaxf(acc[6] + b1.z, 0.f));
        o[7] = (short)f2bf(fmaxf(acc[7] + b1.w, 0.f));
        *(bf16x8*)&outm[(size_t)i * F_HID + g * 8] = o;
    }
}

// ---------------- layer-2 aggregation + log_softmax: 4-parity paired gathers ----------------
__global__ __launch_bounds__(256) void k_agg2(
        const ushort* __restrict__ h, const int2* __restrict__ jw,
        const int* __restrict__ offs, const float* __restrict__ dinv,
        const float* __restrict__ bias, float* __restrict__ outm, int N) {
    int wave = threadIdx.x >> 6, lane = threadIdx.x & 63;
    int i = blockIdx.x * 4 + wave;
    if (i >= N) return;
    int g4 = lane & 15;
    int p  = lane >> 4;
    float di = dinv[i];
    float acc[4];
    {
        bf16x4 hv = *(const bf16x4*)&h[(size_t)i * F_OUT + g4 * 4];
        float w = (p == 0) ? di * di : 0.f;
        #pragma unroll
        for (int k = 0; k < 4; ++k) acc[k] = bf2f((ushort)hv[k]) * w;
    }
    int s = offs[i], e = offs[i + 1];
    for (int u = s; u < e; u += 32) {
        int2 a[8];
        #pragma unroll
        for (int q = 0; q < 8; ++q) a[q] = jw[u + 4 * q + p];
        bf16x4 hv[8];
        #pragma unroll
        for (int q = 0; q < 8; ++q)
            hv[q] = *(const bf16x4*)&h[(size_t)a[q].x * F_OUT + g4 * 4];
        #pragma unroll
        for (int q = 0; q < 8; ++q) {
            float ww = (u + 4 * q + p < e) ? __int_as_float(a[q].y) * di : 0.f;
            #pragma unroll
            for (int k = 0; k < 4; ++k) acc[k] += bf2f((ushort)hv[q][k]) * ww;
        }
    }
    #pragma unroll
    for (int k = 0; k < 4; ++k) {
        acc[k] += __shfl_xor(acc[k], 16, 64);
        acc[k] += __shfl_xor(acc[k], 32, 64);
    }
    float4 bv = *(const float4*)&bias[g4 * 4];
    acc[0] += bv.x; acc[1] += bv.y; acc[2] += bv.z; acc[3] += bv.w;
    float m = fmaxf(fmaxf(acc[0], acc[1]), fmaxf(acc[2], acc[3]));
    #pragma unroll
    for (int o = 8; o >= 1; o >>= 1) m = fmaxf(m, __shfl_xor(m, o, 64));
    float ssum = expf(acc[0] - m) + expf(acc[1] - m) + expf(acc[2] - m) + expf(acc[3] - m);
    #pragma unroll
    for (int o = 8; o >= 1; o >>= 1) ssum += __shfl_xor(ssum, o, 64);
    float lse = m + logf(ssum);
    if (p == 0) {
        float4 o4;
        o4.x = acc[0] - lse; o4.y = acc[1] - lse;
        o4.z = acc[2] - lse; o4.w = acc[3] - lse;
        *(float4*)&outm[(size_t)i * F_OUT + g4 * 4] = o4;
    }
}

extern "C" void kernel_launch(void* const* d_in, const int* in_sizes, int n_in,
                              void* d_out, int out_size, void* d_ws, size_t ws_size,
                              hipStream_t stream) {
    const float* x  = (const float*)d_in[0];
    const int*   ei = (const int*)d_in[1];
    const float* W1 = (const float*)d_in[2];
    const float* b1 = (const float*)d_in[3];
    const float* W2 = (const float*)d_in[4];
    const float* b2 = (const float*)d_in[5];
    float* out = (float*)d_out;

    int N = in_sizes[0] / F_IN;   // 50000
    int E = in_sizes[1] / 2;      // 800000
    const int* src = ei;
    const int* dst = ei + E;

    // workspace layout (16B aligned by construction)
    ushort* w1t = (ushort*)d_ws;                        // 256*512
    ushort* w2t = w1t + F_HID * F_IN;                   // 64*256
    ushort* h1  = w2t + F_OUT * F_HID;                  // N*256 bf16
    ushort* a1  = h1 + (size_t)N * F_HID;               // N*256 bf16
    int*    deg = (int*)(a1 + (size_t)N * F_HID);       // N
    float*  dinv = (float*)(deg + N);                   // N
    int*    offs = (int*)(dinv + N);                    // N+1
    int*    cursor = offs + N + 1;                      // N
    int*    bsums  = cursor + N;                        // 256
    int2*   jw = (int2*)(((uintptr_t)(bsums + 256) + 7) & ~(uintptr_t)7);  // E+32
    ushort* h2 = h1;     // alias: h1 dead after agg1

    int nch = (N + 255) / 256;
    int nyblk = (N + 63) / 64;

    // 1) zero deg + coalesced transpose-casts of W1/W2
    k_prep<<<144, 256, 0, stream>>>(W1, w1t, W2, w2t, deg, N);

    // 2) fused cast+GEMM layer 1 (+ interleaved degree histogram)
    k_gemm1<<<2 * nyblk, 256, 0, stream>>>(x, w1t, h1, N, nyblk, dst, deg, E);

    // 3-6) CSR build: scan1+dinv / scan2 / scan3+pad / fill
    k_scan1<<<nch, 256, 0, stream>>>(deg, offs, bsums, dinv, N);
    k_scan2<<<1, 256, 0, stream>>>(bsums, nch);
    k_scan3<<<nch, 256, 0, stream>>>(offs, bsums, cursor, jw, N, E);
    k_fill<<<(E + 255) / 256, 256, 0, stream>>>(src, dst, cursor, jw, dinv, E);

    // 7) layer-1 aggregate
    k_agg1<<<(N + 3) / 4, 256, 0, stream>>>(h1, jw, offs, dinv, b1, a1, N);

    // 8) layer-2 GEMM
    k_gemm_bf16<4, 1, 1, 4><<<dim3(1, (N + 63) / 64), 256, 0, stream>>>(
        a1, w2t, h2, N, F_HID, F_OUT);

    // 9) layer-2 aggregate + log_softmax
    k_agg2<<<(N + 3) / 4, 256, 0, stream>>>(h2, jw, offs, dinv, b2, out, N);
}